// Round 15
// baseline (304.444 us; speedup 1.0000x reference)
//
#include <hip/hip_runtime.h>
#include <math.h>

#define Lc 13
#define Hc 1024
#define Bc 32
#define Sc 2048
#define BSc (Bc*Sc)
#define CHUNK 128
#define NCHUNK 16
#define NBLK (Bc*NCHUNK)   // 512 chunk blocks

#define GRID_A 512         // 2 stripes/block, uniform residency
#define WU32   (Lc*512)    // 6656 u32 = 26.6 KB bf16 W

#define INV_LN2 1.44269504088896340736f
#define LN2f    0.69314718055994530942f

#if __has_builtin(__builtin_amdgcn_exp2f)
#define EXP2F(x) __builtin_amdgcn_exp2f(x)
#else
#define EXP2F(x) exp2f(x)
#endif
#if __has_builtin(__builtin_amdgcn_logf)
#define LOG2F(x) __builtin_amdgcn_logf(x)
#else
#define LOG2F(x) log2f(x)
#endif

// DPP-based partial butterfly: v += lane-permuted v (VALU only, no LDS).
template <int CTRL>
__device__ __forceinline__ float dpp_add(float v) {
  int p = __builtin_amdgcn_update_dpp(0, __float_as_int(v), CTRL, 0xF, 0xF, true);
  return v + __int_as_float(p);
}

// ---------------------------------------------------------------------------
// Kernel A: logits = hs @ W^T + b.  R10 structure (measured best) with:
// (1) bf16 W in LDS: ds_read_b64 (~6cyc) instead of b128 (~12cyc) halves the
//     ~33us/CU LDS occupancy; unpack is 1 VALU/value (bf16->f32 == u<<16).
//     W staged with RNE rounding; logits err ~1e-2 (threshold-safe margin).
// (2) grid 512 x 2 stripes/block: uniform residency at any blocks/CU, W
//     staged once per block; slice rotation is continuous across stripes
//     (K = s*16+kk, slot = K%3, all literals under full unroll) so stripe-2
//     slices 0,1 load during stripe-1's epilogue.
// Lane = rin*16+ch; per slice: 2 A dwordx4 (HBM), 13 ds_read_b64 + 52 unpack
// + 104 FMA; pure-DPP 16-lane reduction. (512,6): ~75 VGPR target, no spill
// (WRITE_SIZE ~3.5MB tripwire).
// ---------------------------------------------------------------------------
__global__ __launch_bounds__(512, 6)
void k_logits(const float* __restrict__ A, const float* __restrict__ W,
              const float* __restrict__ bias, float* __restrict__ out) {
  __shared__ unsigned Wb[WU32];   // 26.6 KB, bf16 pairs (lo=even h, hi=odd h)
  const int tid = threadIdx.x;
  const int ln  = tid & 63;
  const int wv  = tid >> 6;            // 0..7
  const int rin = ln >> 4;             // row within 4-row group
  const int ch  = ln & 15;             // 16B chunk within 64-float slice

  const size_t rb0 = (size_t)blockIdx.x * 64 + (size_t)wv * 8;          // stripe 0
  const size_t rb1 = rb0 + (size_t)GRID_A * 64;                          // stripe 1
  const float* S0A0 = A + (rb0 + rin) * (size_t)Hc + ch * 4;
  const float* S0A1 = S0A0 + 4 * (size_t)Hc;
  const float* S1A0 = A + (rb1 + rin) * (size_t)Hc + ch * 4;
  const float* S1A1 = S1A0 + 4 * (size_t)Hc;

  // prefetch stripe-0 slices 0,1 (slots 0,1) before W-stage
  float4 b00 = *(const float4*)(S0A0);
  float4 b10 = *(const float4*)(S0A1);
  float4 b01 = *(const float4*)(S0A0 + 64);
  float4 b11 = *(const float4*)(S0A1 + 64);
  __builtin_amdgcn_sched_barrier(0);

  { // stage W as RNE-rounded bf16 pairs: 13 rounds x 512 thr covers 6656 u32
    const unsigned* Wg = (const unsigned*)W;   // f32 bit patterns
#pragma unroll
    for (int i = 0; i < 13; ++i) {
      int j = tid + i * 512;                   // u32 index == float-pair index
      unsigned x0 = Wg[2 * j];
      unsigned x1 = Wg[2 * j + 1];
      unsigned r0 = (x0 + 0x7FFFu + ((x0 >> 16) & 1u)) >> 16;
      unsigned r1 = (x1 + 0x7FFFu + ((x1 >> 16) & 1u)) >> 16;
      Wb[j] = r0 | (r1 << 16);
    }
  }
  __syncthreads();

  float acc0[Lc], acc1[Lc];
#pragma unroll
  for (int l = 0; l < Lc; ++l) { acc0[l] = 0.f; acc1[l] = 0.f; }

  float4 b02, b12;   // slot 2

#pragma unroll
  for (int s = 0; s < 2; ++s) {
    const float* A0 = (s == 0) ? S0A0 : S1A0;
    const float* A1 = (s == 0) ? S0A1 : S1A1;
#pragma unroll
    for (int kk = 0; kk < 16; ++kk) {
      const int K = s * 16 + kk;               // global slice index, literal
      // consume slot K%3
      float4 a0 = (K % 3 == 0) ? b00 : (K % 3 == 1) ? b01 : b02;
      float4 a1 = (K % 3 == 0) ? b10 : (K % 3 == 1) ? b11 : b12;
      // load slice K+2 into slot (K+2)%3 (crosses into stripe 1 at s=0 tail)
      if (K + 2 < 32) {
        const int nk = (K + 2) & 15;
        const float* N0 = (K + 2 < 16) ? A0 : S1A0;
        const float* N1 = (K + 2 < 16) ? A1 : S1A1;
        float4 n0 = *(const float4*)(N0 + nk * 64);
        float4 n1 = *(const float4*)(N1 + nk * 64);
        if ((K + 2) % 3 == 0)      { b00 = n0; b10 = n1; }
        else if ((K + 2) % 3 == 1) { b01 = n0; b11 = n1; }
        else                       { b02 = n0; b12 = n1; }
      }
      const unsigned* wq = &Wb[kk * 32 + ch * 2];
#pragma unroll
      for (int l = 0; l < Lc; ++l) {
        uint2 wp = *(const uint2*)(wq + l * 512);
        float w0 = __uint_as_float(wp.x << 16);
        float w1 = __uint_as_float(wp.x & 0xffff0000u);
        float w2 = __uint_as_float(wp.y << 16);
        float w3 = __uint_as_float(wp.y & 0xffff0000u);
        acc0[l] = fmaf(a0.x, w0, acc0[l]); acc0[l] = fmaf(a0.y, w1, acc0[l]);
        acc0[l] = fmaf(a0.z, w2, acc0[l]); acc0[l] = fmaf(a0.w, w3, acc0[l]);
        acc1[l] = fmaf(a1.x, w0, acc1[l]); acc1[l] = fmaf(a1.y, w1, acc1[l]);
        acc1[l] = fmaf(a1.z, w2, acc1[l]); acc1[l] = fmaf(a1.w, w3, acc1[l]);
      }
    }
    // epilogue for stripe s: DPP reduce within 16-lane groups, store, reset
    const size_t rowBase = (s == 0) ? rb0 : rb1;
#pragma unroll
    for (int l = 0; l < Lc; ++l) {
      float s0 = acc0[l], s1 = acc1[l];
      s0 = dpp_add<0xB1>(s0);   s1 = dpp_add<0xB1>(s1);
      s0 = dpp_add<0x4E>(s0);   s1 = dpp_add<0x4E>(s1);
      s0 = dpp_add<0x141>(s0);  s1 = dpp_add<0x141>(s1);
      s0 = dpp_add<0x140>(s0);  s1 = dpp_add<0x140>(s1);
      acc0[l] = s0; acc1[l] = s1;
    }
    float ov0 = 0.f, ov1 = 0.f;
#pragma unroll
    for (int l = 0; l < Lc; ++l) {
      float bl = bias[l];
      ov0 = (ch == l) ? acc0[l] + bl : ov0;
      ov1 = (ch == l) ? acc1[l] + bl : ov1;
    }
    if (ch < Lc) {
      out[(rowBase + rin) * Lc + ch]     = ov0;
      out[(rowBase + 4 + rin) * Lc + ch] = ov1;
    }
#pragma unroll
    for (int l = 0; l < Lc; ++l) { acc0[l] = 0.f; acc1[l] = 0.f; }
  }
}

// ---------------------------------------------------------------------------
// Kernel B: per (batch, chunk) 13x13 transfer matrix, LINEAR domain
// (13 shfl + 13 fma + 1 exp2 per step; exponent-extract renorm every 8).
// Wave 0 also computes the chunk's numerator partial. Block 0 zeroes out0.
// ---------------------------------------------------------------------------
__global__ void k_chunks(const float* __restrict__ logits, const int* __restrict__ mask,
                         const int* __restrict__ labels, const float* __restrict__ T,
                         float* __restrict__ Mout, float* __restrict__ numpart,
                         float* __restrict__ cntpart, float* __restrict__ out0) {
  const int bp = blockIdx.x;
  const int b  = bp >> 4;       // NCHUNK == 16
  const int p  = bp & 15;
  const int tid = threadIdx.x;
  if (bp == 0 && tid == 0) out0[0] = 0.f;   // zero loss accumulator for k_final
  const int g = tid >> 4;
  const int k = tid & 15;
  const int kk = (k < 13) ? k : 0;
  const int gg = (g < 13) ? g : 0;
  const bool active = (g < 13) && (k < 13);
  const size_t lbase = (size_t)b * Sc;
  const int t0 = 1 + p * CHUNK;
  const int t1 = min(t0 + CHUNK, Sc);

  float U[13];   // column kk of exp(T)
#pragma unroll
  for (int j = 0; j < 13; ++j) U[j] = EXP2F(T[j * 13 + kk] * INV_LN2);

  float e0 = logits[(lbase + t0) * Lc + kk] * INV_LN2;
  int   m0 = mask[lbase + t0];
  float P = m0 ? EXP2F(T[gg * 13 + kk] * INV_LN2 + e0) : ((g == k) ? 1.f : 0.f);
  float off = 0.f;

  for (int t = t0 + 1; t < t1; ++t) {
    float e2 = logits[(lbase + t) * Lc + kk] * INV_LN2;
    int   mk = mask[lbase + t];
    float pj[13];
#pragma unroll
    for (int j = 0; j < 13; ++j) pj[j] = __shfl(P, j, 16);
    float s0 = pj[0] * U[0];  s0 = fmaf(pj[4],  U[4],  s0);
    s0 = fmaf(pj[8],  U[8],  s0);  s0 = fmaf(pj[12], U[12], s0);
    float s1 = pj[1] * U[1];  s1 = fmaf(pj[5],  U[5],  s1);  s1 = fmaf(pj[9],  U[9],  s1);
    float s2 = pj[2] * U[2];  s2 = fmaf(pj[6],  U[6],  s2);  s2 = fmaf(pj[10], U[10], s2);
    float s3 = pj[3] * U[3];  s3 = fmaf(pj[7],  U[7],  s3);  s3 = fmaf(pj[11], U[11], s3);
    float s = (s0 + s1) + (s2 + s3);
    float Pn = EXP2F(e2) * s;
    P = mk ? Pn : P;
    if (((t - t0) & 7) == 0) {   // renorm: keep row max in [1,2)
      float mx = P;
#pragma unroll
      for (int o = 1; o < 16; o <<= 1) mx = fmaxf(mx, __shfl_xor(mx, o, 16));
      unsigned eb = (__float_as_uint(mx) >> 23) & 255u;
      float scale = __uint_as_float((254u - eb) << 23);   // 2^(127-eb)
      P *= scale;
      off += (float)((int)eb - 127);
    }
  }
  if (active) Mout[(size_t)bp * 169 + g * 13 + k] = (P > 0.f) ? (LOG2F(P) + off) : -1e30f;

  // ---- numerator partial for this chunk's tokens [t0, t1) ----
  if (tid < 64) {
    float np = 0.f; int cnt = 0;
    for (int t = t0 + tid; t < t1; t += 64) {
      int mk = mask[lbase + t];
      if (mk) {
        int tg = labels[lbase + t];
        int pg = labels[lbase + t - 1];
        np += T[pg * 13 + tg] + logits[(lbase + t) * Lc + tg];
        cnt += 1;
      }
    }
#pragma unroll
    for (int o = 1; o < 64; o <<= 1) {
      np  += __shfl_xor(np, o, 64);
      cnt += __shfl_xor(cnt, o, 64);
    }
    if (tid == 0) { numpart[bp] = np; cntpart[bp] = (float)cnt; }
  }
}

// ---------------------------------------------------------------------------
// Kernel C: per batch: combine 16 chunk matrices (log2 domain) -> denominator;
// assemble numerator from partials; atomicAdd loss.
// ---------------------------------------------------------------------------
__global__ void k_final(const float* __restrict__ logits, const int* __restrict__ mask,
                        const int* __restrict__ labels, const float* __restrict__ startT,
                        const float* __restrict__ endT, const float* __restrict__ Mws,
                        const float* __restrict__ numpart, const float* __restrict__ cntpart,
                        float* __restrict__ out0) {
  const int b = blockIdx.x;
  const int lane = threadIdx.x;
  const int kk = (lane < 13) ? lane : 0;
  const size_t lbase = (size_t)b * Sc;

  // ---- denominator (log2 domain) ----
  float v = (startT[kk] + logits[lbase * Lc + kk]) * INV_LN2;
  for (int p = 0; p < NCHUNK; ++p) {
    const float* Mp = Mws + (size_t)(b * NCHUNK + p) * 169;
    float a[13];
#pragma unroll
    for (int j = 0; j < 13; ++j) a[j] = __shfl(v, j, 64) + Mp[j * 13 + kk];
    float mx = a[0];
#pragma unroll
    for (int j = 1; j < 13; ++j) mx = fmaxf(mx, a[j]);
    float s = 0.f;
#pragma unroll
    for (int j = 0; j < 13; ++j) s += EXP2F(a[j] - mx);
    v = mx + LOG2F(s);
  }
  float x = (lane < 13) ? (v + endT[kk] * INV_LN2) : -1e30f;
  float mx = x;
#pragma unroll
  for (int off = 1; off < 16; off <<= 1) mx = fmaxf(mx, __shfl_xor(mx, off, 16));
  float sx = EXP2F(x - mx);
#pragma unroll
  for (int off = 1; off < 16; off <<= 1) sx += __shfl_xor(sx, off, 16);
  float den = (mx + LOG2F(sx)) * LN2f;   // valid on lanes 0..15

  // ---- numerator from chunk partials (lanes 0..15) ----
  float np = 0.f, cs = 0.f;
  if (lane < NCHUNK) { np = numpart[b * NCHUNK + lane]; cs = cntpart[b * NCHUNK + lane]; }
#pragma unroll
  for (int o = 1; o < 16; o <<= 1) {
    np += __shfl_xor(np, o, 16);
    cs += __shfl_xor(cs, o, 16);
  }
  if (lane == 0) {
    int lab0 = labels[lbase];
    int seqlen = mask[lbase] + (int)(cs + 0.5f);
    int lastTag = labels[lbase + seqlen - 1];
    float num = startT[lab0] + logits[lbase * Lc + lab0] + np + endT[lastTag];
    float llh = num - den;
    atomicAdd(out0, -llh * (1.0f / Bc));
  }
}

extern "C" void kernel_launch(void* const* d_in, const int* in_sizes, int n_in,
                              void* d_out, int out_size, void* d_ws, size_t ws_size,
                              hipStream_t stream) {
  const float* hs     = (const float*)d_in[0];
  const int*   amask  = (const int*)d_in[1];
  const int*   labels = (const int*)d_in[2];
  const float* W      = (const float*)d_in[3];
  const float* bias   = (const float*)d_in[4];
  const float* startT = (const float*)d_in[5];
  const float* endT   = (const float*)d_in[6];
  const float* T      = (const float*)d_in[7];

  float* out    = (float*)d_out;
  float* logits = out + 1;            // output 1 follows the scalar loss
  float* Mws    = (float*)d_ws;       // 512*169 floats = 346 KB
  float* numpart = Mws + (size_t)NBLK * 169;
  float* cntpart = numpart + NBLK;    // total ~350 KB of ws

  k_logits<<<GRID_A, 512, 0, stream>>>(hs, W, bias, logits);
  k_chunks<<<NBLK, 256, 0, stream>>>(logits, amask, labels, T, Mws, numpart, cntpart, out);
  k_final <<<Bc, 64, 0, stream>>>(logits, amask, labels, startT, endT, Mws, numpart, cntpart, out);
}

// Round 16
// 282.872 us; speedup vs baseline: 1.0763x; 1.0763x over previous
//
#include <hip/hip_runtime.h>
#include <math.h>

#define Lc 13
#define Hc 1024
#define Bc 32
#define Sc 2048
#define BSc (Bc*Sc)
#define CHUNK 128
#define NCHUNK 16
#define NBLK (Bc*NCHUNK)   // 512 chunk blocks

#define WU32   (Lc*512)    // 6656 u32 = 26.6 KB bf16 W

#define INV_LN2 1.44269504088896340736f
#define LN2f    0.69314718055994530942f

#if __has_builtin(__builtin_amdgcn_exp2f)
#define EXP2F(x) __builtin_amdgcn_exp2f(x)
#else
#define EXP2F(x) exp2f(x)
#endif
#if __has_builtin(__builtin_amdgcn_logf)
#define LOG2F(x) __builtin_amdgcn_logf(x)
#else
#define LOG2F(x) log2f(x)
#endif

// DPP-based partial butterfly: v += lane-permuted v (VALU only, no LDS).
template <int CTRL>
__device__ __forceinline__ float dpp_add(float v) {
  int p = __builtin_amdgcn_update_dpp(0, __float_as_int(v), CTRL, 0xF, 0xF, true);
  return v + __int_as_float(p);
}

// ---------------------------------------------------------------------------
// Kernel A: logits = hs @ W^T + b.  STRICT minimal delta from R10 (104us
// champion): identical grid (1024), lane layout (rin*16+ch), depth-2 3-slot
// rotation, DPP reduce -- only the W LDS format changes: bf16 pairs
// (26.6 KB), ds_read_b64 + shift-unpack instead of ds_read_b128. Halves the
// dominant ~33us/CU LDS-read occupancy (R14 model: HBM 43 + LDS 33 + VALU 13
// ~ 84us). R15's spill came from cross-stripe live state, NOT the format
// (absmax 0.0156 proved numerics OK); live set here ~70 < 85-reg cap at
// (512,6). Spill tripwire: WRITE_SIZE must stay ~3.5MB.
// ---------------------------------------------------------------------------
__global__ __launch_bounds__(512, 6)
void k_logits(const float* __restrict__ A, const float* __restrict__ W,
              const float* __restrict__ bias, float* __restrict__ out) {
  __shared__ unsigned Wb[WU32];   // bf16 pairs (lo=even h, hi=odd h)
  const int tid = threadIdx.x;
  const int ln  = tid & 63;
  const int wv  = tid >> 6;            // 0..7
  const int rin = ln >> 4;             // row within 4-row group
  const int ch  = ln & 15;             // 16B chunk within 64-float slice
  const size_t rowBase = (size_t)blockIdx.x * 64 + (size_t)wv * 8;

  const float* A0 = A + (rowBase + rin) * (size_t)Hc + ch * 4;  // g=0 row
  const float* A1 = A0 + 4 * (size_t)Hc;                        // g=1 row

  // depth-2 prefetch: slices 0,1 issued before W-stage
  float4 buf00 = *(const float4*)(A0);
  float4 buf10 = *(const float4*)(A1);
  float4 buf01 = *(const float4*)(A0 + 64);
  float4 buf11 = *(const float4*)(A1 + 64);
  __builtin_amdgcn_sched_barrier(0);   // pin A prefetch first

  { // stage W as RNE-rounded bf16 pairs: 13 rounds x 512 thr = 6656 u32
    const unsigned* Wg = (const unsigned*)W;   // f32 bit patterns
#pragma unroll
    for (int i = 0; i < 13; ++i) {
      int j = tid + i * 512;                   // u32 index == float-pair index
      unsigned x0 = Wg[2 * j];
      unsigned x1 = Wg[2 * j + 1];
      unsigned r0 = (x0 + 0x7FFFu + ((x0 >> 16) & 1u)) >> 16;
      unsigned r1 = (x1 + 0x7FFFu + ((x1 >> 16) & 1u)) >> 16;
      Wb[j] = r0 | (r1 << 16);
    }
  }
  __syncthreads();

  float acc0[Lc], acc1[Lc];
#pragma unroll
  for (int l = 0; l < Lc; ++l) { acc0[l] = 0.f; acc1[l] = 0.f; }

  float4 buf02, buf12;   // slot 2 of the 3-slot rotation
#pragma unroll
  for (int kk = 0; kk < 16; ++kk) {
    // consume slot kk%3 (static under full unroll)
    float4 a0 = (kk % 3 == 0) ? buf00 : (kk % 3 == 1) ? buf01 : buf02;
    float4 a1 = (kk % 3 == 0) ? buf10 : (kk % 3 == 1) ? buf11 : buf12;
    // issue slice kk+2 into slot (kk+2)%3
    if (kk + 2 < 16) {
      float4 n0 = *(const float4*)(A0 + (kk + 2) * 64);
      float4 n1 = *(const float4*)(A1 + (kk + 2) * 64);
      if ((kk + 2) % 3 == 0)      { buf00 = n0; buf10 = n1; }
      else if ((kk + 2) % 3 == 1) { buf01 = n0; buf11 = n1; }
      else                        { buf02 = n0; buf12 = n1; }
    }
    const unsigned* wq = &Wb[kk * 32 + ch * 2];
#pragma unroll
    for (int l = 0; l < Lc; ++l) {
      uint2 wp = *(const uint2*)(wq + l * 512);     // ds_read_b64
      float w0 = __uint_as_float(wp.x << 16);
      float w1 = __uint_as_float(wp.x & 0xffff0000u);
      float w2 = __uint_as_float(wp.y << 16);
      float w3 = __uint_as_float(wp.y & 0xffff0000u);
      acc0[l] = fmaf(a0.x, w0, acc0[l]); acc0[l] = fmaf(a0.y, w1, acc0[l]);
      acc0[l] = fmaf(a0.z, w2, acc0[l]); acc0[l] = fmaf(a0.w, w3, acc0[l]);
      acc1[l] = fmaf(a1.x, w0, acc1[l]); acc1[l] = fmaf(a1.y, w1, acc1[l]);
      acc1[l] = fmaf(a1.z, w2, acc1[l]); acc1[l] = fmaf(a1.w, w3, acc1[l]);
    }
  }

  // reduce within 16-lane group: xor1,xor2 (quad_perm), ^7, ^15 (mirrors)
#pragma unroll
  for (int l = 0; l < Lc; ++l) {
    float s0 = acc0[l], s1 = acc1[l];
    s0 = dpp_add<0xB1>(s0);   s1 = dpp_add<0xB1>(s1);
    s0 = dpp_add<0x4E>(s0);   s1 = dpp_add<0x4E>(s1);
    s0 = dpp_add<0x141>(s0);  s1 = dpp_add<0x141>(s1);
    s0 = dpp_add<0x140>(s0);  s1 = dpp_add<0x140>(s1);
    acc0[l] = s0; acc1[l] = s1;
  }
  float ov0 = 0.f, ov1 = 0.f;
#pragma unroll
  for (int l = 0; l < Lc; ++l) {
    float bl = bias[l];
    ov0 = (ch == l) ? acc0[l] + bl : ov0;
    ov1 = (ch == l) ? acc1[l] + bl : ov1;
  }
  if (ch < Lc) {
    out[(rowBase + rin) * Lc + ch]     = ov0;
    out[(rowBase + 4 + rin) * Lc + ch] = ov1;
  }
}

// ---------------------------------------------------------------------------
// Kernel B: per (batch, chunk) 13x13 transfer matrix, LINEAR domain
// (13 shfl + 13 fma + 1 exp2 per step; exponent-extract renorm every 8).
// Wave 0 also computes the chunk's numerator partial. Block 0 zeroes out0.
// ---------------------------------------------------------------------------
__global__ void k_chunks(const float* __restrict__ logits, const int* __restrict__ mask,
                         const int* __restrict__ labels, const float* __restrict__ T,
                         float* __restrict__ Mout, float* __restrict__ numpart,
                         float* __restrict__ cntpart, float* __restrict__ out0) {
  const int bp = blockIdx.x;
  const int b  = bp >> 4;       // NCHUNK == 16
  const int p  = bp & 15;
  const int tid = threadIdx.x;
  if (bp == 0 && tid == 0) out0[0] = 0.f;   // zero loss accumulator for k_final
  const int g = tid >> 4;
  const int k = tid & 15;
  const int kk = (k < 13) ? k : 0;
  const int gg = (g < 13) ? g : 0;
  const bool active = (g < 13) && (k < 13);
  const size_t lbase = (size_t)b * Sc;
  const int t0 = 1 + p * CHUNK;
  const int t1 = min(t0 + CHUNK, Sc);

  float U[13];   // column kk of exp(T)
#pragma unroll
  for (int j = 0; j < 13; ++j) U[j] = EXP2F(T[j * 13 + kk] * INV_LN2);

  float e0 = logits[(lbase + t0) * Lc + kk] * INV_LN2;
  int   m0 = mask[lbase + t0];
  float P = m0 ? EXP2F(T[gg * 13 + kk] * INV_LN2 + e0) : ((g == k) ? 1.f : 0.f);
  float off = 0.f;

  for (int t = t0 + 1; t < t1; ++t) {
    float e2 = logits[(lbase + t) * Lc + kk] * INV_LN2;
    int   mk = mask[lbase + t];
    float pj[13];
#pragma unroll
    for (int j = 0; j < 13; ++j) pj[j] = __shfl(P, j, 16);
    float s0 = pj[0] * U[0];  s0 = fmaf(pj[4],  U[4],  s0);
    s0 = fmaf(pj[8],  U[8],  s0);  s0 = fmaf(pj[12], U[12], s0);
    float s1 = pj[1] * U[1];  s1 = fmaf(pj[5],  U[5],  s1);  s1 = fmaf(pj[9],  U[9],  s1);
    float s2 = pj[2] * U[2];  s2 = fmaf(pj[6],  U[6],  s2);  s2 = fmaf(pj[10], U[10], s2);
    float s3 = pj[3] * U[3];  s3 = fmaf(pj[7],  U[7],  s3);  s3 = fmaf(pj[11], U[11], s3);
    float s = (s0 + s1) + (s2 + s3);
    float Pn = EXP2F(e2) * s;
    P = mk ? Pn : P;
    if (((t - t0) & 7) == 0) {   // renorm: keep row max in [1,2)
      float mx = P;
#pragma unroll
      for (int o = 1; o < 16; o <<= 1) mx = fmaxf(mx, __shfl_xor(mx, o, 16));
      unsigned eb = (__float_as_uint(mx) >> 23) & 255u;
      float scale = __uint_as_float((254u - eb) << 23);   // 2^(127-eb)
      P *= scale;
      off += (float)((int)eb - 127);
    }
  }
  if (active) Mout[(size_t)bp * 169 + g * 13 + k] = (P > 0.f) ? (LOG2F(P) + off) : -1e30f;

  // ---- numerator partial for this chunk's tokens [t0, t1) ----
  if (tid < 64) {
    float np = 0.f; int cnt = 0;
    for (int t = t0 + tid; t < t1; t += 64) {
      int mk = mask[lbase + t];
      if (mk) {
        int tg = labels[lbase + t];
        int pg = labels[lbase + t - 1];
        np += T[pg * 13 + tg] + logits[(lbase + t) * Lc + tg];
        cnt += 1;
      }
    }
#pragma unroll
    for (int o = 1; o < 64; o <<= 1) {
      np  += __shfl_xor(np, o, 64);
      cnt += __shfl_xor(cnt, o, 64);
    }
    if (tid == 0) { numpart[bp] = np; cntpart[bp] = (float)cnt; }
  }
}

// ---------------------------------------------------------------------------
// Kernel C: per batch: combine 16 chunk matrices (log2 domain) -> denominator;
// assemble numerator from partials; atomicAdd loss.
// ---------------------------------------------------------------------------
__global__ void k_final(const float* __restrict__ logits, const int* __restrict__ mask,
                        const int* __restrict__ labels, const float* __restrict__ startT,
                        const float* __restrict__ endT, const float* __restrict__ Mws,
                        const float* __restrict__ numpart, const float* __restrict__ cntpart,
                        float* __restrict__ out0) {
  const int b = blockIdx.x;
  const int lane = threadIdx.x;
  const int kk = (lane < 13) ? lane : 0;
  const size_t lbase = (size_t)b * Sc;

  // ---- denominator (log2 domain) ----
  float v = (startT[kk] + logits[lbase * Lc + kk]) * INV_LN2;
  for (int p = 0; p < NCHUNK; ++p) {
    const float* Mp = Mws + (size_t)(b * NCHUNK + p) * 169;
    float a[13];
#pragma unroll
    for (int j = 0; j < 13; ++j) a[j] = __shfl(v, j, 64) + Mp[j * 13 + kk];
    float mx = a[0];
#pragma unroll
    for (int j = 1; j < 13; ++j) mx = fmaxf(mx, a[j]);
    float s = 0.f;
#pragma unroll
    for (int j = 0; j < 13; ++j) s += EXP2F(a[j] - mx);
    v = mx + LOG2F(s);
  }
  float x = (lane < 13) ? (v + endT[kk] * INV_LN2) : -1e30f;
  float mx = x;
#pragma unroll
  for (int off = 1; off < 16; off <<= 1) mx = fmaxf(mx, __shfl_xor(mx, off, 16));
  float sx = EXP2F(x - mx);
#pragma unroll
  for (int off = 1; off < 16; off <<= 1) sx += __shfl_xor(sx, off, 16);
  float den = (mx + LOG2F(sx)) * LN2f;   // valid on lanes 0..15

  // ---- numerator from chunk partials (lanes 0..15) ----
  float np = 0.f, cs = 0.f;
  if (lane < NCHUNK) { np = numpart[b * NCHUNK + lane]; cs = cntpart[b * NCHUNK + lane]; }
#pragma unroll
  for (int o = 1; o < 16; o <<= 1) {
    np += __shfl_xor(np, o, 16);
    cs += __shfl_xor(cs, o, 16);
  }
  if (lane == 0) {
    int lab0 = labels[lbase];
    int seqlen = mask[lbase] + (int)(cs + 0.5f);
    int lastTag = labels[lbase + seqlen - 1];
    float num = startT[lab0] + logits[lbase * Lc + lab0] + np + endT[lastTag];
    float llh = num - den;
    atomicAdd(out0, -llh * (1.0f / Bc));
  }
}

extern "C" void kernel_launch(void* const* d_in, const int* in_sizes, int n_in,
                              void* d_out, int out_size, void* d_ws, size_t ws_size,
                              hipStream_t stream) {
  const float* hs     = (const float*)d_in[0];
  const int*   amask  = (const int*)d_in[1];
  const int*   labels = (const int*)d_in[2];
  const float* W      = (const float*)d_in[3];
  const float* bias   = (const float*)d_in[4];
  const float* startT = (const float*)d_in[5];
  const float* endT   = (const float*)d_in[6];
  const float* T      = (const float*)d_in[7];

  float* out    = (float*)d_out;
  float* logits = out + 1;            // output 1 follows the scalar loss
  float* Mws    = (float*)d_ws;       // 512*169 floats = 346 KB
  float* numpart = Mws + (size_t)NBLK * 169;
  float* cntpart = numpart + NBLK;    // total ~350 KB of ws

  k_logits<<<BSc / 64, 512, 0, stream>>>(hs, W, bias, logits);
  k_chunks<<<NBLK, 256, 0, stream>>>(logits, amask, labels, T, Mws, numpart, cntpart, out);
  k_final <<<Bc, 64, 0, stream>>>(logits, amask, labels, startT, endT, Mws, numpart, cntpart, out);
}

// Round 17
// 105.947 us; speedup vs baseline: 2.8735x; 2.6699x over previous
//
#include <hip/hip_runtime.h>
#include <math.h>

#define Lc 13
#define Hc 1024
#define Bc 32
#define Sc 2048
#define BSc (Bc*Sc)
#define CHUNK 128
#define NCHUNK 16
#define NBLK (Bc*NCHUNK)   // 512 chunk blocks

#define WU32   (Lc*512)    // 6656 u32 = 26.6 KB bf16 W

#define INV_LN2 1.44269504088896340736f
#define LN2f    0.69314718055994530942f

#if __has_builtin(__builtin_amdgcn_exp2f)
#define EXP2F(x) __builtin_amdgcn_exp2f(x)
#else
#define EXP2F(x) exp2f(x)
#endif
#if __has_builtin(__builtin_amdgcn_logf)
#define LOG2F(x) __builtin_amdgcn_logf(x)
#else
#define LOG2F(x) log2f(x)
#endif

// DPP-based partial butterfly: v += lane-permuted v (VALU only, no LDS).
template <int CTRL>
__device__ __forceinline__ float dpp_add(float v) {
  int p = __builtin_amdgcn_update_dpp(0, __float_as_int(v), CTRL, 0xF, 0xF, true);
  return v + __int_as_float(p);
}

// ---------------------------------------------------------------------------
// Kernel A: logits = hs @ W^T + b.  R10 structure + bf16 W (ds_read_b64,
// halves the dominant ~33us/CU LDS term) under __launch_bounds__(512,2) --
// the ONLY bound measured spill-free for ~100-reg bodies on this toolchain:
// (512,2)->128 clean (R7/R8); (512,4)->64 spilled (R12); (512,6) collapsed
// to VGPR=40 + 300MB scratch twice (R15/R16). Occupancy 4 waves/SIMD; R8 ran
// this exact config cleanly. Live set ~75 regs. Spill tripwire: WRITE_SIZE
// must be ~3.5MB, VGPR >= 90.
// ---------------------------------------------------------------------------
__global__ __launch_bounds__(512, 2)
void k_logits(const float* __restrict__ A, const float* __restrict__ W,
              const float* __restrict__ bias, float* __restrict__ out) {
  __shared__ unsigned Wb[WU32];   // bf16 pairs (lo=even h, hi=odd h)
  const int tid = threadIdx.x;
  const int ln  = tid & 63;
  const int wv  = tid >> 6;            // 0..7
  const int rin = ln >> 4;             // row within 4-row group
  const int ch  = ln & 15;             // 16B chunk within 64-float slice
  const size_t rowBase = (size_t)blockIdx.x * 64 + (size_t)wv * 8;

  const float* A0 = A + (rowBase + rin) * (size_t)Hc + ch * 4;  // g=0 row
  const float* A1 = A0 + 4 * (size_t)Hc;                        // g=1 row

  // depth-2 prefetch: slices 0,1 issued before W-stage
  float4 buf00 = *(const float4*)(A0);
  float4 buf10 = *(const float4*)(A1);
  float4 buf01 = *(const float4*)(A0 + 64);
  float4 buf11 = *(const float4*)(A1 + 64);
  __builtin_amdgcn_sched_barrier(0);   // pin A prefetch first

  { // stage W as RNE-rounded bf16 pairs: 13 rounds x 512 thr = 6656 u32
    const unsigned* Wg = (const unsigned*)W;   // f32 bit patterns
#pragma unroll
    for (int i = 0; i < 13; ++i) {
      int j = tid + i * 512;                   // u32 index == float-pair index
      unsigned x0 = Wg[2 * j];
      unsigned x1 = Wg[2 * j + 1];
      unsigned r0 = (x0 + 0x7FFFu + ((x0 >> 16) & 1u)) >> 16;
      unsigned r1 = (x1 + 0x7FFFu + ((x1 >> 16) & 1u)) >> 16;
      Wb[j] = r0 | (r1 << 16);
    }
  }
  __syncthreads();

  float acc0[Lc], acc1[Lc];
#pragma unroll
  for (int l = 0; l < Lc; ++l) { acc0[l] = 0.f; acc1[l] = 0.f; }

  float4 buf02, buf12;   // slot 2 of the 3-slot rotation
#pragma unroll
  for (int kk = 0; kk < 16; ++kk) {
    // consume slot kk%3 (static under full unroll)
    float4 a0 = (kk % 3 == 0) ? buf00 : (kk % 3 == 1) ? buf01 : buf02;
    float4 a1 = (kk % 3 == 0) ? buf10 : (kk % 3 == 1) ? buf11 : buf12;
    // issue slice kk+2 into slot (kk+2)%3
    if (kk + 2 < 16) {
      float4 n0 = *(const float4*)(A0 + (kk + 2) * 64);
      float4 n1 = *(const float4*)(A1 + (kk + 2) * 64);
      if ((kk + 2) % 3 == 0)      { buf00 = n0; buf10 = n1; }
      else if ((kk + 2) % 3 == 1) { buf01 = n0; buf11 = n1; }
      else                        { buf02 = n0; buf12 = n1; }
    }
    const unsigned* wq = &Wb[kk * 32 + ch * 2];
#pragma unroll
    for (int l = 0; l < Lc; ++l) {
      uint2 wp = *(const uint2*)(wq + l * 512);     // ds_read_b64
      float w0 = __uint_as_float(wp.x << 16);
      float w1 = __uint_as_float(wp.x & 0xffff0000u);
      float w2 = __uint_as_float(wp.y << 16);
      float w3 = __uint_as_float(wp.y & 0xffff0000u);
      acc0[l] = fmaf(a0.x, w0, acc0[l]); acc0[l] = fmaf(a0.y, w1, acc0[l]);
      acc0[l] = fmaf(a0.z, w2, acc0[l]); acc0[l] = fmaf(a0.w, w3, acc0[l]);
      acc1[l] = fmaf(a1.x, w0, acc1[l]); acc1[l] = fmaf(a1.y, w1, acc1[l]);
      acc1[l] = fmaf(a1.z, w2, acc1[l]); acc1[l] = fmaf(a1.w, w3, acc1[l]);
    }
  }

  // reduce within 16-lane group: xor1,xor2 (quad_perm), ^7, ^15 (mirrors)
#pragma unroll
  for (int l = 0; l < Lc; ++l) {
    float s0 = acc0[l], s1 = acc1[l];
    s0 = dpp_add<0xB1>(s0);   s1 = dpp_add<0xB1>(s1);
    s0 = dpp_add<0x4E>(s0);   s1 = dpp_add<0x4E>(s1);
    s0 = dpp_add<0x141>(s0);  s1 = dpp_add<0x141>(s1);
    s0 = dpp_add<0x140>(s0);  s1 = dpp_add<0x140>(s1);
    acc0[l] = s0; acc1[l] = s1;
  }
  float ov0 = 0.f, ov1 = 0.f;
#pragma unroll
  for (int l = 0; l < Lc; ++l) {
    float bl = bias[l];
    ov0 = (ch == l) ? acc0[l] + bl : ov0;
    ov1 = (ch == l) ? acc1[l] + bl : ov1;
  }
  if (ch < Lc) {
    out[(rowBase + rin) * Lc + ch]     = ov0;
    out[(rowBase + 4 + rin) * Lc + ch] = ov1;
  }
}

// ---------------------------------------------------------------------------
// Kernel B: per (batch, chunk) 13x13 transfer matrix, LINEAR domain
// (13 shfl + 13 fma + 1 exp2 per step; exponent-extract renorm every 8).
// Wave 0 also computes the chunk's numerator partial. Block 0 zeroes out0.
// ---------------------------------------------------------------------------
__global__ void k_chunks(const float* __restrict__ logits, const int* __restrict__ mask,
                         const int* __restrict__ labels, const float* __restrict__ T,
                         float* __restrict__ Mout, float* __restrict__ numpart,
                         float* __restrict__ cntpart, float* __restrict__ out0) {
  const int bp = blockIdx.x;
  const int b  = bp >> 4;       // NCHUNK == 16
  const int p  = bp & 15;
  const int tid = threadIdx.x;
  if (bp == 0 && tid == 0) out0[0] = 0.f;   // zero loss accumulator for k_final
  const int g = tid >> 4;
  const int k = tid & 15;
  const int kk = (k < 13) ? k : 0;
  const int gg = (g < 13) ? g : 0;
  const bool active = (g < 13) && (k < 13);
  const size_t lbase = (size_t)b * Sc;
  const int t0 = 1 + p * CHUNK;
  const int t1 = min(t0 + CHUNK, Sc);

  float U[13];   // column kk of exp(T)
#pragma unroll
  for (int j = 0; j < 13; ++j) U[j] = EXP2F(T[j * 13 + kk] * INV_LN2);

  float e0 = logits[(lbase + t0) * Lc + kk] * INV_LN2;
  int   m0 = mask[lbase + t0];
  float P = m0 ? EXP2F(T[gg * 13 + kk] * INV_LN2 + e0) : ((g == k) ? 1.f : 0.f);
  float off = 0.f;

  for (int t = t0 + 1; t < t1; ++t) {
    float e2 = logits[(lbase + t) * Lc + kk] * INV_LN2;
    int   mk = mask[lbase + t];
    float pj[13];
#pragma unroll
    for (int j = 0; j < 13; ++j) pj[j] = __shfl(P, j, 16);
    float s0 = pj[0] * U[0];  s0 = fmaf(pj[4],  U[4],  s0);
    s0 = fmaf(pj[8],  U[8],  s0);  s0 = fmaf(pj[12], U[12], s0);
    float s1 = pj[1] * U[1];  s1 = fmaf(pj[5],  U[5],  s1);  s1 = fmaf(pj[9],  U[9],  s1);
    float s2 = pj[2] * U[2];  s2 = fmaf(pj[6],  U[6],  s2);  s2 = fmaf(pj[10], U[10], s2);
    float s3 = pj[3] * U[3];  s3 = fmaf(pj[7],  U[7],  s3);  s3 = fmaf(pj[11], U[11], s3);
    float s = (s0 + s1) + (s2 + s3);
    float Pn = EXP2F(e2) * s;
    P = mk ? Pn : P;
    if (((t - t0) & 7) == 0) {   // renorm: keep row max in [1,2)
      float mx = P;
#pragma unroll
      for (int o = 1; o < 16; o <<= 1) mx = fmaxf(mx, __shfl_xor(mx, o, 16));
      unsigned eb = (__float_as_uint(mx) >> 23) & 255u;
      float scale = __uint_as_float((254u - eb) << 23);   // 2^(127-eb)
      P *= scale;
      off += (float)((int)eb - 127);
    }
  }
  if (active) Mout[(size_t)bp * 169 + g * 13 + k] = (P > 0.f) ? (LOG2F(P) + off) : -1e30f;

  // ---- numerator partial for this chunk's tokens [t0, t1) ----
  if (tid < 64) {
    float np = 0.f; int cnt = 0;
    for (int t = t0 + tid; t < t1; t += 64) {
      int mk = mask[lbase + t];
      if (mk) {
        int tg = labels[lbase + t];
        int pg = labels[lbase + t - 1];
        np += T[pg * 13 + tg] + logits[(lbase + t) * Lc + tg];
        cnt += 1;
      }
    }
#pragma unroll
    for (int o = 1; o < 64; o <<= 1) {
      np  += __shfl_xor(np, o, 64);
      cnt += __shfl_xor(cnt, o, 64);
    }
    if (tid == 0) { numpart[bp] = np; cntpart[bp] = (float)cnt; }
  }
}

// ---------------------------------------------------------------------------
// Kernel C: per batch: combine 16 chunk matrices (log2 domain) -> denominator;
// assemble numerator from partials; atomicAdd loss.
// ---------------------------------------------------------------------------
__global__ void k_final(const float* __restrict__ logits, const int* __restrict__ mask,
                        const int* __restrict__ labels, const float* __restrict__ startT,
                        const float* __restrict__ endT, const float* __restrict__ Mws,
                        const float* __restrict__ numpart, const float* __restrict__ cntpart,
                        float* __restrict__ out0) {
  const int b = blockIdx.x;
  const int lane = threadIdx.x;
  const int kk = (lane < 13) ? lane : 0;
  const size_t lbase = (size_t)b * Sc;

  // ---- denominator (log2 domain) ----
  float v = (startT[kk] + logits[lbase * Lc + kk]) * INV_LN2;
  for (int p = 0; p < NCHUNK; ++p) {
    const float* Mp = Mws + (size_t)(b * NCHUNK + p) * 169;
    float a[13];
#pragma unroll
    for (int j = 0; j < 13; ++j) a[j] = __shfl(v, j, 64) + Mp[j * 13 + kk];
    float mx = a[0];
#pragma unroll
    for (int j = 1; j < 13; ++j) mx = fmaxf(mx, a[j]);
    float s = 0.f;
#pragma unroll
    for (int j = 0; j < 13; ++j) s += EXP2F(a[j] - mx);
    v = mx + LOG2F(s);
  }
  float x = (lane < 13) ? (v + endT[kk] * INV_LN2) : -1e30f;
  float mx = x;
#pragma unroll
  for (int off = 1; off < 16; off <<= 1) mx = fmaxf(mx, __shfl_xor(mx, off, 16));
  float sx = EXP2F(x - mx);
#pragma unroll
  for (int off = 1; off < 16; off <<= 1) sx += __shfl_xor(sx, off, 16);
  float den = (mx + LOG2F(sx)) * LN2f;   // valid on lanes 0..15

  // ---- numerator from chunk partials (lanes 0..15) ----
  float np = 0.f, cs = 0.f;
  if (lane < NCHUNK) { np = numpart[b * NCHUNK + lane]; cs = cntpart[b * NCHUNK + lane]; }
#pragma unroll
  for (int o = 1; o < 16; o <<= 1) {
    np += __shfl_xor(np, o, 16);
    cs += __shfl_xor(cs, o, 16);
  }
  if (lane == 0) {
    int lab0 = labels[lbase];
    int seqlen = mask[lbase] + (int)(cs + 0.5f);
    int lastTag = labels[lbase + seqlen - 1];
    float num = startT[lab0] + logits[lbase * Lc + lab0] + np + endT[lastTag];
    float llh = num - den;
    atomicAdd(out0, -llh * (1.0f / Bc));
  }
}

extern "C" void kernel_launch(void* const* d_in, const int* in_sizes, int n_in,
                              void* d_out, int out_size, void* d_ws, size_t ws_size,
                              hipStream_t stream) {
  const float* hs     = (const float*)d_in[0];
  const int*   amask  = (const int*)d_in[1];
  const int*   labels = (const int*)d_in[2];
  const float* W      = (const float*)d_in[3];
  const float* bias   = (const float*)d_in[4];
  const float* startT = (const float*)d_in[5];
  const float* endT   = (const float*)d_in[6];
  const float* T      = (const float*)d_in[7];

  float* out    = (float*)d_out;
  float* logits = out + 1;            // output 1 follows the scalar loss
  float* Mws    = (float*)d_ws;       // 512*169 floats = 346 KB
  float* numpart = Mws + (size_t)NBLK * 169;
  float* cntpart = numpart + NBLK;    // total ~350 KB of ws

  k_logits<<<BSc / 64, 512, 0, stream>>>(hs, W, bias, logits);
  k_chunks<<<NBLK, 256, 0, stream>>>(logits, amask, labels, T, Mws, numpart, cntpart, out);
  k_final <<<Bc, 64, 0, stream>>>(logits, amask, labels, startT, endT, Mws, numpart, cntpart, out);
}